// Round 1
// baseline (981.130 us; speedup 1.0000x reference)
//
#include <hip/hip_runtime.h>
#include <math.h>
#include <float.h>

namespace {

constexpr int B  = 2;
constexpr int CK = 64;
constexpr int N  = 12960;   // T*H*W = 8*30*54
constexpr int M  = 1620;    // H*W = 30*54
constexpr int CV = 384;
constexpr int K  = 20;      // topk (setup fixed)

// K1: a_sq[b,n] = sum_c mk[b,c,n]^2
__global__ __launch_bounds__(256) void asq_kernel(const float* __restrict__ mk,
                                                  float* __restrict__ asq) {
  int i = blockIdx.x * 256 + threadIdx.x;
  if (i >= B * N) return;
  int b = i / N, n = i - b * N;
  const float* p = mk + (size_t)b * CK * N + n;
  float s = 0.f;
#pragma unroll
  for (int c = 0; c < CK; ++c) {
    float v = p[(size_t)c * N];
    s += v * v;
  }
  asq[i] = s;
}

// K2: affinity^T tile: aff[b][mi][n] = (2*dot(mk[:,n], qk[:,m]) - asq[n]) / 8
// block = 256 threads: 64 n-groups (4 consecutive n each) x 4 m-groups (4 m each)
__global__ __launch_bounds__(256) void aff_kernel(const float* __restrict__ mk,
                                                  const float* __restrict__ qk,
                                                  const float* __restrict__ asq,
                                                  float* __restrict__ aff,
                                                  int m0, int mcAct, int mcAlloc) {
  int b = blockIdx.z;
  int mbase = blockIdx.y * 16;  // column-tile base within chunk
  __shared__ float qs[16][CK];
  int t = threadIdx.x;
  for (int l = t; l < 16 * CK; l += 256) {
    int jj = l >> 6, c = l & 63;
    int mg = m0 + mbase + jj;  // global m
    qs[jj][c] = (mbase + jj < mcAct) ? qk[((size_t)b * CK + c) * M + mg] : 0.f;
  }
  __syncthreads();

  int n0 = blockIdx.x * 256 + (t & 63) * 4;
  int jg = (t >> 6) * 4;           // 0,4,8,12
  if (n0 >= N) return;             // N%4==0 -> lanes fully valid or fully invalid

  const float* mkb = mk + (size_t)b * CK * N + n0;
  float4 a0 = {0.f, 0.f, 0.f, 0.f}, a1 = a0, a2 = a0, a3 = a0;
#pragma unroll 8
  for (int c = 0; c < CK; ++c) {
    const float4 kv = *reinterpret_cast<const float4*>(mkb + (size_t)c * N);
    float q0 = qs[jg + 0][c], q1 = qs[jg + 1][c], q2 = qs[jg + 2][c], q3 = qs[jg + 3][c];
    a0.x += kv.x * q0; a0.y += kv.y * q0; a0.z += kv.z * q0; a0.w += kv.w * q0;
    a1.x += kv.x * q1; a1.y += kv.y * q1; a1.z += kv.z * q1; a1.w += kv.w * q1;
    a2.x += kv.x * q2; a2.y += kv.y * q2; a2.z += kv.z * q2; a2.w += kv.w * q2;
    a3.x += kv.x * q3; a3.y += kv.y * q3; a3.z += kv.z * q3; a3.w += kv.w * q3;
  }
  const float4 sq = *reinterpret_cast<const float4*>(asq + (size_t)b * N + n0);

  float4 accs[4] = {a0, a1, a2, a3};
#pragma unroll
  for (int jj = 0; jj < 4; ++jj) {
    int mi = mbase + jg + jj;
    if (mi < mcAct) {
      float4 r;
      r.x = (2.f * accs[jj].x - sq.x) * 0.125f;
      r.y = (2.f * accs[jj].y - sq.y) * 0.125f;
      r.z = (2.f * accs[jj].z - sq.z) * 0.125f;
      r.w = (2.f * accs[jj].w - sq.w) * 0.125f;
      *reinterpret_cast<float4*>(aff + ((size_t)b * mcAlloc + mi) * N + n0) = r;
    }
  }
}

// K3: exact top-20 (stable: value desc, index asc) + softmax per (b, m).
// Ordered threshold descent: each round finds the max strictly below the
// previous winner in (v desc, n asc) lexicographic order -> no register-array
// mutation with dynamic index, exact lax.top_k tie semantics.
__global__ __launch_bounds__(256) void topk_kernel(const float* __restrict__ aff,
                                                   int m0, int mcAlloc,
                                                   int* __restrict__ tki,
                                                   float* __restrict__ tkw) {
  int mi = blockIdx.x, b = blockIdx.y;
  const float* row = aff + ((size_t)b * mcAlloc + mi) * N;
  constexpr int J = (N + 255) / 256;  // 51
  float v[J];
  int t = threadIdx.x;
#pragma unroll
  for (int j = 0; j < J; ++j) {
    int n = t + (j << 8);
    v[j] = (n < N) ? row[n] : -FLT_MAX;
  }

  __shared__ float swv[4];
  __shared__ int swn[4];
  __shared__ float topv[K];
  __shared__ int topn[K];
  __shared__ float winv_s;
  __shared__ int winn_s;

  float lastv = FLT_MAX;
  int lastn = -1;
  for (int it = 0; it < K; ++it) {
    float bv = -FLT_MAX;
    int bn = 0x7fffffff;
#pragma unroll
    for (int j = 0; j < J; ++j) {
      int n = t + (j << 8);
      float x = v[j];
      bool ok = (x < lastv) || (x == lastv && n > lastn);
      bool g = ok && ((x > bv) || (x == bv && n < bn));
      bv = g ? x : bv;
      bn = g ? n : bn;
    }
#pragma unroll
    for (int off = 32; off > 0; off >>= 1) {
      float ov = __shfl_down(bv, off);
      int on = __shfl_down(bn, off);
      if ((ov > bv) || (ov == bv && on < bn)) { bv = ov; bn = on; }
    }
    if ((t & 63) == 0) { swv[t >> 6] = bv; swn[t >> 6] = bn; }
    __syncthreads();
    if (t == 0) {
      float Bv = swv[0];
      int Bn = swn[0];
      for (int w = 1; w < 4; ++w)
        if ((swv[w] > Bv) || (swv[w] == Bv && swn[w] < Bn)) { Bv = swv[w]; Bn = swn[w]; }
      topv[it] = Bv; topn[it] = Bn;
      winv_s = Bv; winn_s = Bn;
    }
    __syncthreads();
    lastv = winv_s;
    lastn = winn_s;
  }

  if (t == 0) {
    float mx = topv[0], s = 0.f;
    float w[K];
#pragma unroll
    for (int j = 0; j < K; ++j) {
      w[j] = expf(topv[j] - mx);
      s += w[j];
    }
    float inv = 1.f / s;
    size_t base = ((size_t)b * M + (m0 + mi)) * K;
#pragma unroll
    for (int j = 0; j < K; ++j) {
      tkw[base + j] = w[j] * inv;
      tki[base + j] = topn[j];
    }
  }
}

// K4: out[b][c][m] = sum_j w_j * mv[b][c][idx_j]; 384 threads = CV channels.
__global__ __launch_bounds__(384) void gather_kernel(const float* __restrict__ mv,
                                                     const int* __restrict__ tki,
                                                     const float* __restrict__ tkw,
                                                     int m0, float* __restrict__ out) {
  int m = m0 + blockIdx.x, b = blockIdx.y;
  __shared__ int si[K];
  __shared__ float sw[K];
  int t = threadIdx.x;
  size_t base = ((size_t)b * M + m) * K;
  if (t < K) {
    si[t] = tki[base + t];
    sw[t] = tkw[base + t];
  }
  __syncthreads();
  const float* mvb = mv + (size_t)b * CV * N + (size_t)t * N;
  float s = 0.f;
#pragma unroll
  for (int j = 0; j < K; ++j) s += sw[j] * mvb[si[j]];
  out[((size_t)b * CV + t) * M + m] = s;
}

}  // namespace

extern "C" void kernel_launch(void* const* d_in, const int* in_sizes, int n_in,
                              void* d_out, int out_size, void* d_ws, size_t ws_size,
                              hipStream_t stream) {
  const float* mk = (const float*)d_in[0];
  const float* qk = (const float*)d_in[1];
  const float* mv = (const float*)d_in[2];
  float* out = (float*)d_out;

  char* w = (char*)d_ws;
  float* asq = (float*)w;
  size_t o = (size_t)B * N * sizeof(float);          // 103680
  int* tki = (int*)(w + o);
  o += (size_t)B * M * K * sizeof(int);              // +259200
  float* tkw = (float*)(w + o);
  o += (size_t)B * M * K * sizeof(float);            // +259200
  float* aff = (float*)(w + o);

  // chunk M so the fp32 affinity buffer [B][mcAlloc][N] fits in workspace
  size_t avail = (ws_size > o) ? (ws_size - o) : 0;
  long cols = (long)(avail / ((size_t)B * N * sizeof(float)));
  int mcAlloc = (int)(cols & ~15L);
  if (mcAlloc < 16) mcAlloc = 16;      // best-effort floor
  if (mcAlloc > 1632) mcAlloc = 1632;  // single-chunk cap

  asq_kernel<<<(B * N + 255) / 256, 256, 0, stream>>>(mk, asq);

  for (int m0 = 0; m0 < M; m0 += mcAlloc) {
    int mcAct = (M - m0 < mcAlloc) ? (M - m0) : mcAlloc;
    dim3 ga((N + 255) / 256, (mcAct + 15) / 16, B);
    aff_kernel<<<ga, 256, 0, stream>>>(mk, qk, asq, aff, m0, mcAct, mcAlloc);
    topk_kernel<<<dim3(mcAct, B), 256, 0, stream>>>(aff, m0, mcAlloc, tki, tkw);
    gather_kernel<<<dim3(mcAct, B), 384, 0, stream>>>(mv, tki, tkw, m0, out);
  }
}

// Round 2
// 505.375 us; speedup vs baseline: 1.9414x; 1.9414x over previous
//
#include <hip/hip_runtime.h>
#include <math.h>
#include <float.h>
#include <limits.h>
#include <stdint.h>

namespace {

constexpr int B  = 2;
constexpr int CK = 64;
constexpr int N  = 12960;   // T*H*W = 8*30*54
constexpr int M  = 1620;    // H*W = 30*54
constexpr int CV = 384;
constexpr int K  = 20;      // topk (setup fixed)
constexpr int J  = (N + 255) / 256;  // 51 values per thread in topk

// monotone float->uint key (order-preserving) and inverse
__device__ __forceinline__ uint32_t f2k(float x) {
  uint32_t u = __float_as_uint(x);
  return u ^ ((u & 0x80000000u) ? 0xFFFFFFFFu : 0x80000000u);
}
__device__ __forceinline__ float k2f(uint32_t k) {
  uint32_t u = (k & 0x80000000u) ? (k ^ 0x80000000u) : ~k;
  return __uint_as_float(u);
}

// K1: a_sq[b,n] = sum_c mk[b,c,n]^2
__global__ __launch_bounds__(256) void asq_kernel(const float* __restrict__ mk,
                                                  float* __restrict__ asq) {
  int i = blockIdx.x * 256 + threadIdx.x;
  if (i >= B * N) return;
  int b = i / N, n = i - b * N;
  const float* p = mk + (size_t)b * CK * N + n;
  float s = 0.f;
#pragma unroll
  for (int c = 0; c < CK; ++c) {
    float v = p[(size_t)c * N];
    s += v * v;
  }
  asq[i] = s;
}

// K2: affinity^T tile: aff[b][mi][n] = (2*dot(mk[:,n], qk[:,m]) - asq[n]) / 8
// IDENTICAL to round 1 (same summation order -> same rank-20 set).
__global__ __launch_bounds__(256) void aff_kernel(const float* __restrict__ mk,
                                                  const float* __restrict__ qk,
                                                  const float* __restrict__ asq,
                                                  float* __restrict__ aff,
                                                  int m0, int mcAct, int mcAlloc) {
  int b = blockIdx.z;
  int mbase = blockIdx.y * 16;  // column-tile base within chunk
  __shared__ float qs[16][CK];
  int t = threadIdx.x;
  for (int l = t; l < 16 * CK; l += 256) {
    int jj = l >> 6, c = l & 63;
    int mg = m0 + mbase + jj;  // global m
    qs[jj][c] = (mbase + jj < mcAct) ? qk[((size_t)b * CK + c) * M + mg] : 0.f;
  }
  __syncthreads();

  int n0 = blockIdx.x * 256 + (t & 63) * 4;
  int jg = (t >> 6) * 4;           // 0,4,8,12
  if (n0 >= N) return;             // N%4==0 -> lanes fully valid or fully invalid

  const float* mkb = mk + (size_t)b * CK * N + n0;
  float4 a0 = {0.f, 0.f, 0.f, 0.f}, a1 = a0, a2 = a0, a3 = a0;
#pragma unroll 8
  for (int c = 0; c < CK; ++c) {
    const float4 kv = *reinterpret_cast<const float4*>(mkb + (size_t)c * N);
    float q0 = qs[jg + 0][c], q1 = qs[jg + 1][c], q2 = qs[jg + 2][c], q3 = qs[jg + 3][c];
    a0.x += kv.x * q0; a0.y += kv.y * q0; a0.z += kv.z * q0; a0.w += kv.w * q0;
    a1.x += kv.x * q1; a1.y += kv.y * q1; a1.z += kv.z * q1; a1.w += kv.w * q1;
    a2.x += kv.x * q2; a2.y += kv.y * q2; a2.z += kv.z * q2; a2.w += kv.w * q2;
    a3.x += kv.x * q3; a3.y += kv.y * q3; a3.z += kv.z * q3; a3.w += kv.w * q3;
  }
  const float4 sq = *reinterpret_cast<const float4*>(asq + (size_t)b * N + n0);

  float4 accs[4] = {a0, a1, a2, a3};
#pragma unroll
  for (int jj = 0; jj < 4; ++jj) {
    int mi = mbase + jg + jj;
    if (mi < mcAct) {
      float4 r;
      r.x = (2.f * accs[jj].x - sq.x) * 0.125f;
      r.y = (2.f * accs[jj].y - sq.y) * 0.125f;
      r.z = (2.f * accs[jj].z - sq.z) * 0.125f;
      r.w = (2.f * accs[jj].w - sq.w) * 0.125f;
      *reinterpret_cast<float4*>(aff + ((size_t)b * mcAlloc + mi) * N + n0) = r;
    }
  }
}

// K3: exact top-20 via 4-pass (8-bit) radix select on the monotone key.
// Ties at the boundary filled by ascending index -> exact lax.top_k winner set.
// Softmax is order-invariant w.r.t. the scatter, so winners need no sorting.
__global__ __launch_bounds__(256) void topk_kernel(const float* __restrict__ aff,
                                                   int m0, int mcAlloc,
                                                   int* __restrict__ tki,
                                                   float* __restrict__ tkw) {
  const int mi = blockIdx.x, b = blockIdx.y;
  const float* row = aff + ((size_t)b * mcAlloc + mi) * N;
  const int t = threadIdx.x;

  uint32_t k[J];
#pragma unroll
  for (int j = 0; j < J; ++j) {
    int n = t + (j << 8);
    k[j] = (n < N) ? f2k(row[n]) : 0u;  // key 0 == negative NaN, below all real data
  }

  constexpr int HP = 264;  // skewed per-wave histogram stride (264 % 32 = 8 banks apart)
  __shared__ int hist[4 * HP];
  __shared__ int s_digit, s_before;
  __shared__ int wn[K];
  __shared__ uint32_t wk[K];
  __shared__ int gcnt, ecnt, s_last;
  __shared__ int ebuf[K];
  __shared__ int rmin4[4];

  int before = 0;       // count of keys > current prefix region
  uint32_t pref = 0;    // resolved high bits, right-aligned
  const int w = t >> 6;

  for (int p = 0; p < 4; ++p) {
    const int s = 24 - 8 * p;
    for (int l = t; l < 4 * HP; l += 256) hist[l] = 0;
    __syncthreads();
    const int shHi = (p == 0) ? 0 : (s + 8);
#pragma unroll
    for (int j = 0; j < J; ++j) {
      uint32_t key = k[j];
      bool act = (p == 0) || ((key >> shHi) == pref);
      if (act) atomicAdd(&hist[w * HP + ((key >> s) & 255)], 1);
    }
    __syncthreads();
    if (t < 64) {
      // lane t owns digits 4t..4t+3
      int d = 4 * t;
      int g0 = hist[d] + hist[HP + d] + hist[2 * HP + d] + hist[3 * HP + d];
      int g1 = hist[d + 1] + hist[HP + d + 1] + hist[2 * HP + d + 1] + hist[3 * HP + d + 1];
      int g2 = hist[d + 2] + hist[HP + d + 2] + hist[2 * HP + d + 2] + hist[3 * HP + d + 2];
      int g3 = hist[d + 3] + hist[HP + d + 3] + hist[2 * HP + d + 3] + hist[3 * HP + d + 3];
      int sl = g0 + g1 + g2 + g3;
      int sfx = sl;  // inclusive suffix-sum across lanes (digits >= 4t)
#pragma unroll
      for (int off = 1; off < 64; off <<= 1) {
        int o = __shfl_down(sfx, off);
        sfx += (t + off < 64) ? o : 0;
      }
      int above = sfx - sl;     // count of keys in digits >= 4(t+1)
      int rem = K - before;
      if (above < rem && rem <= sfx) {  // boundary digit is in my group (exactly one lane)
        int cum = above, ds;
        if (cum + g3 >= rem) ds = 3;
        else { cum += g3;
          if (cum + g2 >= rem) ds = 2;
          else { cum += g2;
            if (cum + g1 >= rem) ds = 1;
            else { cum += g1; ds = 0; } } }
        s_digit = 4 * t + ds;
        s_before = before + cum;
      }
    }
    __syncthreads();
    pref = (pref << 8) | (uint32_t)s_digit;
    before = s_before;
  }

  const uint32_t thr = pref;       // exact key of the K-th ranked element
  const int need = K - before;     // winners still to take among key == thr (1..K)
  if (t == 0) { gcnt = 0; ecnt = 0; }
  __syncthreads();
#pragma unroll
  for (int j = 0; j < J; ++j) {
    uint32_t key = k[j];
    int n = t + (j << 8);
    if (key > thr) {
      int q = atomicAdd(&gcnt, 1);
      wn[q] = n; wk[q] = key;      // exactly `before` of these by construction
    } else if (key == thr) {
      int q = atomicAdd(&ecnt, 1);
      if (q < K) ebuf[q] = n;
    }
  }
  __syncthreads();
  if (ecnt == need) {              // common case (no boundary tie: need==1, ecnt==1)
    if (t < need) { wn[before + t] = ebuf[t]; wk[before + t] = thr; }
  } else {
    // rare: pick `need` smallest indices among key == thr (exact tie semantics)
    int last = -1;
    for (int r = 0; r < need; ++r) {
      int loc = INT_MAX;
#pragma unroll
      for (int j = 0; j < J; ++j) {
        int n = t + (j << 8);
        if (k[j] == thr && n > last && n < loc) loc = n;
      }
#pragma unroll
      for (int off = 1; off < 64; off <<= 1) loc = min(loc, __shfl_xor(loc, off));
      if ((t & 63) == 0) rmin4[t >> 6] = loc;
      __syncthreads();
      if (t == 0) {
        int mn = min(min(rmin4[0], rmin4[1]), min(rmin4[2], rmin4[3]));
        wn[before + r] = mn; wk[before + r] = thr; s_last = mn;
      }
      __syncthreads();
      last = s_last;
    }
  }
  __syncthreads();

  // softmax over the K winners (wave 0)
  if (t < 64) {
    float v = (t < K) ? k2f(wk[t]) : -FLT_MAX;
    float mx = v;
#pragma unroll
    for (int off = 1; off < 64; off <<= 1) mx = fmaxf(mx, __shfl_xor(mx, off));
    float e = (t < K) ? expf(v - mx) : 0.f;
    float ss = e;
#pragma unroll
    for (int off = 1; off < 64; off <<= 1) ss += __shfl_xor(ss, off);
    if (t < K) {
      size_t base = ((size_t)b * M + (m0 + mi)) * (size_t)K;
      tkw[base + t] = e / ss;
      tki[base + t] = wn[t];
    }
  }
}

// K4: out[b][c][m] = sum_j w_j * mv[b][c][idx_j]
// block per (b, c): scattered reads stay inside ONE 51.8 KB mv row (L1/L2-hot),
// stores coalesced over m.
__global__ __launch_bounds__(256) void gather_kernel(const float* __restrict__ mv,
                                                     const int* __restrict__ tki,
                                                     const float* __restrict__ tkw,
                                                     int m0, int mcAct,
                                                     float* __restrict__ out) {
  int c = blockIdx.x, b = blockIdx.y;
  const float* row = mv + ((size_t)b * CV + c) * N;
  for (int mi = threadIdx.x; mi < mcAct; mi += 256) {
    int m = m0 + mi;
    size_t base = ((size_t)b * M + m) * (size_t)K;
    float s = 0.f;
#pragma unroll
    for (int j = 0; j < K; ++j) s += tkw[base + j] * row[tki[base + j]];
    out[((size_t)b * CV + c) * M + m] = s;
  }
}

}  // namespace

extern "C" void kernel_launch(void* const* d_in, const int* in_sizes, int n_in,
                              void* d_out, int out_size, void* d_ws, size_t ws_size,
                              hipStream_t stream) {
  const float* mk = (const float*)d_in[0];
  const float* qk = (const float*)d_in[1];
  const float* mv = (const float*)d_in[2];
  float* out = (float*)d_out;

  char* w = (char*)d_ws;
  float* asq = (float*)w;
  size_t o = (size_t)B * N * sizeof(float);          // 103680
  int* tki = (int*)(w + o);
  o += (size_t)B * M * K * sizeof(int);              // +259200
  float* tkw = (float*)(w + o);
  o += (size_t)B * M * K * sizeof(float);            // +259200
  float* aff = (float*)(w + o);

  // chunk M so the fp32 affinity buffer [B][mcAlloc][N] fits in workspace
  size_t avail = (ws_size > o) ? (ws_size - o) : 0;
  long cols = (long)(avail / ((size_t)B * N * sizeof(float)));
  int mcAlloc = (int)(cols & ~15L);
  if (mcAlloc < 16) mcAlloc = 16;      // best-effort floor
  if (mcAlloc > 1632) mcAlloc = 1632;  // single-chunk cap

  asq_kernel<<<(B * N + 255) / 256, 256, 0, stream>>>(mk, asq);

  for (int m0 = 0; m0 < M; m0 += mcAlloc) {
    int mcAct = (M - m0 < mcAlloc) ? (M - m0) : mcAlloc;
    dim3 ga((N + 255) / 256, (mcAct + 15) / 16, B);
    aff_kernel<<<ga, 256, 0, stream>>>(mk, qk, asq, aff, m0, mcAct, mcAlloc);
    topk_kernel<<<dim3(mcAct, B), 256, 0, stream>>>(aff, m0, mcAlloc, tki, tkw);
    gather_kernel<<<dim3(CV, B), 256, 0, stream>>>(mv, tki, tkw, m0, mcAct, out);
  }
}

// Round 3
// 330.737 us; speedup vs baseline: 2.9665x; 1.5280x over previous
//
#include <hip/hip_runtime.h>
#include <math.h>
#include <float.h>
#include <limits.h>
#include <stdint.h>

namespace {

constexpr int B  = 2;
constexpr int CK = 64;
constexpr int N  = 12960;   // T*H*W = 8*30*54
constexpr int M  = 1620;    // H*W = 30*54
constexpr int CV = 384;
constexpr int K  = 20;      // topk (setup fixed)
constexpr int J  = (N + 255) / 256;  // 51 values per thread in topk

// monotone float->uint key (order-preserving) and inverse
__device__ __forceinline__ uint32_t f2k(float x) {
  uint32_t u = __float_as_uint(x);
  return u ^ ((u & 0x80000000u) ? 0xFFFFFFFFu : 0x80000000u);
}
__device__ __forceinline__ float k2f(uint32_t k) {
  uint32_t u = (k & 0x80000000u) ? (k ^ 0x80000000u) : ~k;
  return __uint_as_float(u);
}

// K0: mvT[b][n][c] = mv[b][c][n]  (so gather reads are contiguous in c)
__global__ __launch_bounds__(256) void transpose_kernel(const float* __restrict__ mv,
                                                        float* __restrict__ mvT) {
  __shared__ float tile[64][65];
  int b = blockIdx.z;
  int n0 = blockIdx.x * 64;
  int c0 = blockIdx.y * 64;
  int tx = threadIdx.x & 63, ty = threadIdx.x >> 6;
  for (int r = ty; r < 64; r += 4) {
    int c = c0 + r, n = n0 + tx;
    tile[r][tx] = (n < N) ? mv[((size_t)b * CV + c) * N + n] : 0.f;
  }
  __syncthreads();
  for (int r = ty; r < 64; r += 4) {
    int n = n0 + r, c = c0 + tx;
    if (n < N) mvT[((size_t)b * N + n) * CV + c] = tile[tx][r];
  }
}

// K1: a_sq[b,n] = sum_c mk[b,c,n]^2
__global__ __launch_bounds__(256) void asq_kernel(const float* __restrict__ mk,
                                                  float* __restrict__ asq) {
  int i = blockIdx.x * 256 + threadIdx.x;
  if (i >= B * N) return;
  int b = i / N, n = i - b * N;
  const float* p = mk + (size_t)b * CK * N + n;
  float s = 0.f;
#pragma unroll
  for (int c = 0; c < CK; ++c) {
    float v = p[(size_t)c * N];
    s += v * v;
  }
  asq[i] = s;
}

// K2: affinity^T tile: aff[b][mi][n] = (2*dot(mk[:,n], qk[:,m]) - asq[n]) / 8
// 32 m x 256 n per block; qs transposed [c][m] so per-c LDS reads are two
// broadcast ds_read_b128. Same c-ascending FMA order as before -> bit-identical.
__global__ __launch_bounds__(256) void aff_kernel(const float* __restrict__ mk,
                                                  const float* __restrict__ qk,
                                                  const float* __restrict__ asq,
                                                  float* __restrict__ aff,
                                                  int m0, int mcAct, int mcAlloc) {
  int b = blockIdx.z;
  int mbase = blockIdx.y * 32;
  __shared__ float qs[CK][36];  // stride 36 floats = 144 B (16B-aligned rows)
  int t = threadIdx.x;
  for (int l = t; l < CK * 32; l += 256) {
    int c = l >> 5, ml = l & 31;
    int mg = m0 + mbase + ml;
    qs[c][ml] = (mbase + ml < mcAct) ? qk[((size_t)b * CK + c) * M + mg] : 0.f;
  }
  __syncthreads();

  int n0 = blockIdx.x * 256 + (t & 63) * 4;
  int mg = (t >> 6) * 8;  // 0,8,16,24
  if (n0 >= N) return;    // N%4==0 -> float4 lanes fully valid or fully invalid

  const float* mkb = mk + (size_t)b * CK * N + n0;
  float4 acc[8];
#pragma unroll
  for (int j = 0; j < 8; ++j) acc[j] = make_float4(0.f, 0.f, 0.f, 0.f);

#pragma unroll 4
  for (int c = 0; c < CK; ++c) {
    const float4 kv = *reinterpret_cast<const float4*>(mkb + (size_t)c * N);
    const float4 qa = *reinterpret_cast<const float4*>(&qs[c][mg]);
    const float4 qb = *reinterpret_cast<const float4*>(&qs[c][mg + 4]);
    acc[0].x += kv.x * qa.x; acc[0].y += kv.y * qa.x; acc[0].z += kv.z * qa.x; acc[0].w += kv.w * qa.x;
    acc[1].x += kv.x * qa.y; acc[1].y += kv.y * qa.y; acc[1].z += kv.z * qa.y; acc[1].w += kv.w * qa.y;
    acc[2].x += kv.x * qa.z; acc[2].y += kv.y * qa.z; acc[2].z += kv.z * qa.z; acc[2].w += kv.w * qa.z;
    acc[3].x += kv.x * qa.w; acc[3].y += kv.y * qa.w; acc[3].z += kv.z * qa.w; acc[3].w += kv.w * qa.w;
    acc[4].x += kv.x * qb.x; acc[4].y += kv.y * qb.x; acc[4].z += kv.z * qb.x; acc[4].w += kv.w * qb.x;
    acc[5].x += kv.x * qb.y; acc[5].y += kv.y * qb.y; acc[5].z += kv.z * qb.y; acc[5].w += kv.w * qb.y;
    acc[6].x += kv.x * qb.z; acc[6].y += kv.y * qb.z; acc[6].z += kv.z * qb.z; acc[6].w += kv.w * qb.z;
    acc[7].x += kv.x * qb.w; acc[7].y += kv.y * qb.w; acc[7].z += kv.z * qb.w; acc[7].w += kv.w * qb.w;
  }
  const float4 sq = *reinterpret_cast<const float4*>(asq + (size_t)b * N + n0);
#pragma unroll
  for (int j = 0; j < 8; ++j) {
    int mi = mbase + mg + j;
    if (mi < mcAct) {
      float4 r;
      r.x = (2.f * acc[j].x - sq.x) * 0.125f;
      r.y = (2.f * acc[j].y - sq.y) * 0.125f;
      r.z = (2.f * acc[j].z - sq.z) * 0.125f;
      r.w = (2.f * acc[j].w - sq.w) * 0.125f;
      *reinterpret_cast<float4*>(aff + ((size_t)b * mcAlloc + mi) * N + n0) = r;
    }
  }
}

// K3: exact top-20 via 4-pass radix select + softmax + FUSED gather.
// Gather uses mvT (contiguous in c) -> coalesced reads; weights/idx from LDS.
__global__ __launch_bounds__(256) void topk_gather_kernel(const float* __restrict__ aff,
                                                          const float* __restrict__ mvT,
                                                          int m0, int mcAlloc,
                                                          float* __restrict__ out) {
  const int mi = blockIdx.x, b = blockIdx.y;
  const int m = m0 + mi;
  const float* row = aff + ((size_t)b * mcAlloc + mi) * N;
  const int t = threadIdx.x;

  uint32_t k[J];
#pragma unroll
  for (int j = 0; j < J; ++j) {
    int n = t + (j << 8);
    k[j] = (n < N) ? f2k(row[n]) : 0u;  // key 0 == negative NaN, below all real data
  }

  constexpr int HP = 264;  // skewed per-wave histogram stride
  __shared__ int hist[4 * HP];
  __shared__ int s_digit, s_before;
  __shared__ int wn[K];
  __shared__ uint32_t wk[K];
  __shared__ float sw[K];
  __shared__ int gcnt, ecnt, s_last;
  __shared__ int ebuf[K];
  __shared__ int rmin4[4];

  int before = 0;
  uint32_t pref = 0;
  const int w = t >> 6;

  for (int p = 0; p < 4; ++p) {
    const int s = 24 - 8 * p;
    for (int l = t; l < 4 * HP; l += 256) hist[l] = 0;
    __syncthreads();
    const int shHi = (p == 0) ? 0 : (s + 8);
#pragma unroll
    for (int j = 0; j < J; ++j) {
      uint32_t key = k[j];
      bool act = (p == 0) || ((key >> shHi) == pref);
      if (act) atomicAdd(&hist[w * HP + ((key >> s) & 255)], 1);
    }
    __syncthreads();
    if (t < 64) {
      int d = 4 * t;
      int g0 = hist[d] + hist[HP + d] + hist[2 * HP + d] + hist[3 * HP + d];
      int g1 = hist[d + 1] + hist[HP + d + 1] + hist[2 * HP + d + 1] + hist[3 * HP + d + 1];
      int g2 = hist[d + 2] + hist[HP + d + 2] + hist[2 * HP + d + 2] + hist[3 * HP + d + 2];
      int g3 = hist[d + 3] + hist[HP + d + 3] + hist[2 * HP + d + 3] + hist[3 * HP + d + 3];
      int sl = g0 + g1 + g2 + g3;
      int sfx = sl;
#pragma unroll
      for (int off = 1; off < 64; off <<= 1) {
        int o = __shfl_down(sfx, off);
        sfx += (t + off < 64) ? o : 0;
      }
      int above = sfx - sl;
      int rem = K - before;
      if (above < rem && rem <= sfx) {
        int cum = above, ds;
        if (cum + g3 >= rem) ds = 3;
        else { cum += g3;
          if (cum + g2 >= rem) ds = 2;
          else { cum += g2;
            if (cum + g1 >= rem) ds = 1;
            else { cum += g1; ds = 0; } } }
        s_digit = 4 * t + ds;
        s_before = before + cum;
      }
    }
    __syncthreads();
    pref = (pref << 8) | (uint32_t)s_digit;
    before = s_before;
  }

  const uint32_t thr = pref;
  const int need = K - before;
  if (t == 0) { gcnt = 0; ecnt = 0; }
  __syncthreads();
#pragma unroll
  for (int j = 0; j < J; ++j) {
    uint32_t key = k[j];
    int n = t + (j << 8);
    if (key > thr) {
      int q = atomicAdd(&gcnt, 1);
      wn[q] = n; wk[q] = key;
    } else if (key == thr) {
      int q = atomicAdd(&ecnt, 1);
      if (q < K) ebuf[q] = n;
    }
  }
  __syncthreads();
  if (ecnt == need) {
    if (t < need) { wn[before + t] = ebuf[t]; wk[before + t] = thr; }
  } else {
    int last = -1;
    for (int r = 0; r < need; ++r) {
      int loc = INT_MAX;
#pragma unroll
      for (int j = 0; j < J; ++j) {
        int n = t + (j << 8);
        if (k[j] == thr && n > last && n < loc) loc = n;
      }
#pragma unroll
      for (int off = 1; off < 64; off <<= 1) loc = min(loc, __shfl_xor(loc, off));
      if ((t & 63) == 0) rmin4[t >> 6] = loc;
      __syncthreads();
      if (t == 0) {
        int mn = min(min(rmin4[0], rmin4[1]), min(rmin4[2], rmin4[3]));
        wn[before + r] = mn; wk[before + r] = thr; s_last = mn;
      }
      __syncthreads();
      last = s_last;
    }
  }
  __syncthreads();

  // softmax over the K winners (wave 0)
  if (t < 64) {
    float v = (t < K) ? k2f(wk[t]) : -FLT_MAX;
    float mx = v;
#pragma unroll
    for (int off = 1; off < 64; off <<= 1) mx = fmaxf(mx, __shfl_xor(mx, off));
    float e = (t < K) ? expf(v - mx) : 0.f;
    float ss = e;
#pragma unroll
    for (int off = 1; off < 64; off <<= 1) ss += __shfl_xor(ss, off);
    if (t < K) sw[t] = e / ss;
  }
  __syncthreads();

  // fused gather: out[b][c][m] = sum_j sw[j] * mvT[b][wn[j]][c]
  const float* tb = mvT + (size_t)b * N * CV;
  for (int c = t; c < CV; c += 256) {
    float s = 0.f;
#pragma unroll
    for (int j = 0; j < K; ++j) s += sw[j] * tb[(size_t)wn[j] * CV + c];
    out[((size_t)b * CV + c) * M + m] = s;
  }
}

}  // namespace

extern "C" void kernel_launch(void* const* d_in, const int* in_sizes, int n_in,
                              void* d_out, int out_size, void* d_ws, size_t ws_size,
                              hipStream_t stream) {
  const float* mk = (const float*)d_in[0];
  const float* qk = (const float*)d_in[1];
  const float* mv = (const float*)d_in[2];
  float* out = (float*)d_out;

  char* w = (char*)d_ws;
  float* asq = (float*)w;
  size_t o = (size_t)B * N * sizeof(float);          // 103,680 B
  float* mvT = (float*)(w + o);
  o += (size_t)B * N * CV * sizeof(float);           // +39,813,120 B
  float* aff = (float*)(w + o);

  // chunk M so the fp32 affinity buffer [B][mcAlloc][N] fits in workspace
  size_t avail = (ws_size > o) ? (ws_size - o) : 0;
  long cols = (long)(avail / ((size_t)B * N * sizeof(float)));
  int mcAlloc = (int)(cols & ~31L);
  if (mcAlloc < 32) mcAlloc = 32;      // best-effort floor
  if (mcAlloc > 1632) mcAlloc = 1632;  // single-chunk cap

  transpose_kernel<<<dim3((N + 63) / 64, CV / 64, B), 256, 0, stream>>>(mv, mvT);
  asq_kernel<<<(B * N + 255) / 256, 256, 0, stream>>>(mk, asq);

  for (int m0 = 0; m0 < M; m0 += mcAlloc) {
    int mcAct = (M - m0 < mcAlloc) ? (M - m0) : mcAlloc;
    dim3 ga((N + 255) / 256, (mcAct + 31) / 32, B);
    aff_kernel<<<ga, 256, 0, stream>>>(mk, qk, asq, aff, m0, mcAct, mcAlloc);
    topk_gather_kernel<<<dim3(mcAct, B), 256, 0, stream>>>(aff, mvT, m0, mcAlloc, out);
  }
}

// Round 4
// 330.410 us; speedup vs baseline: 2.9694x; 1.0010x over previous
//
#include <hip/hip_runtime.h>
#include <math.h>
#include <float.h>
#include <limits.h>
#include <stdint.h>

namespace {

constexpr int B  = 2;
constexpr int CK = 64;
constexpr int N  = 12960;   // T*H*W = 8*30*54
constexpr int M  = 1620;    // H*W = 30*54
constexpr int CV = 384;
constexpr int K  = 20;      // topk (setup fixed)
constexpr int JV = 13;      // float4 sweeps per thread: 13*256*4 = 13312 >= 12960
constexpr int JK = 4 * JV;  // 52 keys per thread

// monotone float->uint key (order-preserving) and inverse
__device__ __forceinline__ uint32_t f2k(float x) {
  uint32_t u = __float_as_uint(x);
  return u ^ ((u & 0x80000000u) ? 0xFFFFFFFFu : 0x80000000u);
}
__device__ __forceinline__ float k2f(uint32_t k) {
  uint32_t u = (k & 0x80000000u) ? (k ^ 0x80000000u) : ~k;
  return __uint_as_float(u);
}

// K0: mvT[b][n][c] = mv[b][c][n]  (so gather reads are contiguous in c)
__global__ __launch_bounds__(256) void transpose_kernel(const float* __restrict__ mv,
                                                        float* __restrict__ mvT) {
  __shared__ float tile[64][65];
  int b = blockIdx.z;
  int n0 = blockIdx.x * 64;
  int c0 = blockIdx.y * 64;
  int tx = threadIdx.x & 63, ty = threadIdx.x >> 6;
  for (int r = ty; r < 64; r += 4) {
    int c = c0 + r, n = n0 + tx;
    tile[r][tx] = (n < N) ? mv[((size_t)b * CV + c) * N + n] : 0.f;
  }
  __syncthreads();
  for (int r = ty; r < 64; r += 4) {
    int n = n0 + r, c = c0 + tx;
    if (n < N) mvT[((size_t)b * N + n) * CV + c] = tile[tx][r];
  }
}

// K5: out[b][c][m] = outT[b][m][c]  (kill the stride-M write amplification)
__global__ __launch_bounds__(256) void transpose_out_kernel(const float* __restrict__ outT,
                                                            float* __restrict__ out) {
  __shared__ float tile[64][65];
  int b = blockIdx.z;
  int m0 = blockIdx.x * 64;
  int c0 = blockIdx.y * 64;
  int tx = threadIdx.x & 63, ty = threadIdx.x >> 6;
  for (int r = ty; r < 64; r += 4) {
    int m = m0 + r;
    if (m < M) tile[r][tx] = outT[((size_t)b * M + m) * CV + c0 + tx];
  }
  __syncthreads();
  for (int r = ty; r < 64; r += 4) {
    int c = c0 + r, m = m0 + tx;
    if (m < M) out[((size_t)b * CV + c) * M + m] = tile[tx][r];
  }
}

// K1: a_sq[b,n] = sum_c mk[b,c,n]^2
__global__ __launch_bounds__(256) void asq_kernel(const float* __restrict__ mk,
                                                  float* __restrict__ asq) {
  int i = blockIdx.x * 256 + threadIdx.x;
  if (i >= B * N) return;
  int b = i / N, n = i - b * N;
  const float* p = mk + (size_t)b * CK * N + n;
  float s = 0.f;
#pragma unroll
  for (int c = 0; c < CK; ++c) {
    float v = p[(size_t)c * N];
    s += v * v;
  }
  asq[i] = s;
}

// K2: affinity^T tile: aff[b][mi][n] = (2*dot(mk[:,n], qk[:,m]) - asq[n]) / 8
// 64 m x 256 n per block; thread = 4n x 16m (64 FMA per c, ONE global float4
// per c) -> mk L2 demand ~32 B/cyc/CU, under the ~56 B/cyc L2 ceiling.
// Per-element FMA chain still c-ascending -> same selection as before.
__global__ __launch_bounds__(256) void aff_kernel(const float* __restrict__ mk,
                                                  const float* __restrict__ qk,
                                                  const float* __restrict__ asq,
                                                  float* __restrict__ aff,
                                                  int m0, int mcAct, int mcAlloc) {
  int b = blockIdx.z;
  int mbase = blockIdx.y * 64;
  __shared__ float qs[CK][68];  // row stride 272 B (16B-aligned, non-pow2 banks)
  int t = threadIdx.x;
  for (int l = t; l < CK * 64; l += 256) {
    int c = l >> 6, ml = l & 63;
    int mg = m0 + mbase + ml;
    qs[c][ml] = (mbase + ml < mcAct) ? qk[((size_t)b * CK + c) * M + mg] : 0.f;
  }
  __syncthreads();

  int n0 = blockIdx.x * 256 + (t & 63) * 4;
  int mg = (t >> 6) * 16;  // 0,16,32,48 (wave-uniform -> qs reads broadcast)
  if (n0 >= N) return;

  const float* mkb = mk + (size_t)b * CK * N + n0;
  float4 acc[16];
#pragma unroll
  for (int j = 0; j < 16; ++j) acc[j] = make_float4(0.f, 0.f, 0.f, 0.f);

#pragma unroll 4
  for (int c = 0; c < CK; ++c) {
    const float4 kv = *reinterpret_cast<const float4*>(mkb + (size_t)c * N);
    const float4 q0 = *reinterpret_cast<const float4*>(&qs[c][mg]);
    const float4 q1 = *reinterpret_cast<const float4*>(&qs[c][mg + 4]);
    const float4 q2 = *reinterpret_cast<const float4*>(&qs[c][mg + 8]);
    const float4 q3 = *reinterpret_cast<const float4*>(&qs[c][mg + 12]);
    const float qv[16] = {q0.x, q0.y, q0.z, q0.w, q1.x, q1.y, q1.z, q1.w,
                          q2.x, q2.y, q2.z, q2.w, q3.x, q3.y, q3.z, q3.w};
#pragma unroll
    for (int j = 0; j < 16; ++j) {
      acc[j].x += kv.x * qv[j];
      acc[j].y += kv.y * qv[j];
      acc[j].z += kv.z * qv[j];
      acc[j].w += kv.w * qv[j];
    }
  }
  const float4 sq = *reinterpret_cast<const float4*>(asq + (size_t)b * N + n0);
#pragma unroll
  for (int j = 0; j < 16; ++j) {
    int mi = mbase + mg + j;
    if (mi < mcAct) {
      float4 r;
      r.x = (2.f * acc[j].x - sq.x) * 0.125f;
      r.y = (2.f * acc[j].y - sq.y) * 0.125f;
      r.z = (2.f * acc[j].z - sq.z) * 0.125f;
      r.w = (2.f * acc[j].w - sq.w) * 0.125f;
      *reinterpret_cast<float4*>(aff + ((size_t)b * mcAlloc + mi) * N + n0) = r;
    }
  }
}

__device__ __forceinline__ int nOf(int t, int jj) {  // flat key idx -> n
  return 4 * (t + ((jj >> 2) << 8)) + (jj & 3);
}

// K3: exact top-20 via 4-pass radix select + softmax + fused gather.
// float4 row loads; histogram has 4 sub-replicas/wave (16 lanes each) to cut
// same-address atomic serialization on concentrated digits 64-way -> 16-way.
// Gather writes coalesced float4 rows to outT[b][m][c].
__global__ __launch_bounds__(256) void topk_gather_kernel(const float* __restrict__ aff,
                                                          const float* __restrict__ mvT,
                                                          int m0, int mcAlloc,
                                                          float* __restrict__ outT) {
  const int mi = blockIdx.x, b = blockIdx.y;
  const int m = m0 + mi;
  const float4* row4 = reinterpret_cast<const float4*>(aff + ((size_t)b * mcAlloc + mi) * N);
  const int t = threadIdx.x;

  uint32_t k[JK];
#pragma unroll
  for (int j = 0; j < JV; ++j) {
    int n4 = t + (j << 8);
    if (n4 * 4 < N) {
      float4 v = row4[n4];
      k[4 * j + 0] = f2k(v.x);
      k[4 * j + 1] = f2k(v.y);
      k[4 * j + 2] = f2k(v.z);
      k[4 * j + 3] = f2k(v.w);
    } else {
      k[4 * j + 0] = 0u; k[4 * j + 1] = 0u; k[4 * j + 2] = 0u; k[4 * j + 3] = 0u;
    }
  }

  constexpr int HP = 268;  // 268*4B = 1072 B row: 16B-aligned, non-pow2 bank offset
  __shared__ int hist[4][4][HP];
  __shared__ int s_digit, s_before;
  __shared__ int wn[K];
  __shared__ uint32_t wk[K];
  __shared__ float sw[K];
  __shared__ int gcnt, ecnt, s_last;
  __shared__ int ebuf[K];
  __shared__ int rmin4[4];

  int before = 0;
  uint32_t pref = 0;
  const int w = t >> 6;
  const int rp = (t >> 4) & 3;
  int* myhist = &hist[w][rp][0];

  for (int p = 0; p < 4; ++p) {
    const int s = 24 - 8 * p;
    for (int l = t; l < 16 * HP; l += 256) ((int*)hist)[l] = 0;
    __syncthreads();
    const int shHi = (p == 0) ? 0 : (s + 8);
#pragma unroll
    for (int j = 0; j < JK; ++j) {
      uint32_t key = k[j];
      bool act = (p == 0) || ((key >> shHi) == pref);
      if (act) atomicAdd(&myhist[(key >> s) & 255], 1);
    }
    __syncthreads();
    if (t < 64) {
      int d = 4 * t;
      int4 g = make_int4(0, 0, 0, 0);
#pragma unroll
      for (int ww = 0; ww < 4; ++ww)
#pragma unroll
        for (int rr = 0; rr < 4; ++rr) {
          int4 h = *reinterpret_cast<int4*>(&hist[ww][rr][d]);
          g.x += h.x; g.y += h.y; g.z += h.z; g.w += h.w;
        }
      int sl = g.x + g.y + g.z + g.w;
      int sfx = sl;
#pragma unroll
      for (int off = 1; off < 64; off <<= 1) {
        int o = __shfl_down(sfx, off);
        sfx += (t + off < 64) ? o : 0;
      }
      int above = sfx - sl;
      int rem = K - before;
      if (above < rem && rem <= sfx) {  // boundary digit in my 4-digit group
        int cum = above, ds;
        if (cum + g.w >= rem) ds = 3;
        else { cum += g.w;
          if (cum + g.z >= rem) ds = 2;
          else { cum += g.z;
            if (cum + g.y >= rem) ds = 1;
            else { cum += g.y; ds = 0; } } }
        s_digit = 4 * t + ds;
        s_before = before + cum;
      }
    }
    __syncthreads();
    pref = (pref << 8) | (uint32_t)s_digit;
    before = s_before;
  }

  const uint32_t thr = pref;
  const int need = K - before;
  if (t == 0) { gcnt = 0; ecnt = 0; }
  __syncthreads();
#pragma unroll
  for (int j = 0; j < JK; ++j) {
    uint32_t key = k[j];
    if (key > thr) {
      int q = atomicAdd(&gcnt, 1);
      wn[q] = nOf(t, j); wk[q] = key;
    } else if (key == thr) {
      int q = atomicAdd(&ecnt, 1);
      if (q < K) ebuf[q] = nOf(t, j);
    }
  }
  __syncthreads();
  if (ecnt == need) {
    if (t < need) { wn[before + t] = ebuf[t]; wk[before + t] = thr; }
  } else {
    // rare boundary tie: pick `need` smallest indices among key == thr
    int last = -1;
    for (int r = 0; r < need; ++r) {
      int loc = INT_MAX;
#pragma unroll
      for (int j = 0; j < JK; ++j) {
        int n = nOf(t, j);
        if (k[j] == thr && n > last && n < loc) loc = n;
      }
#pragma unroll
      for (int off = 1; off < 64; off <<= 1) loc = min(loc, __shfl_xor(loc, off));
      if ((t & 63) == 0) rmin4[t >> 6] = loc;
      __syncthreads();
      if (t == 0) {
        int mn = min(min(rmin4[0], rmin4[1]), min(rmin4[2], rmin4[3]));
        wn[before + r] = mn; wk[before + r] = thr; s_last = mn;
      }
      __syncthreads();
      last = s_last;
    }
  }
  __syncthreads();

  // softmax over the K winners (wave 0)
  if (t < 64) {
    float v = (t < K) ? k2f(wk[t]) : -FLT_MAX;
    float mx = v;
#pragma unroll
    for (int off = 1; off < 64; off <<= 1) mx = fmaxf(mx, __shfl_xor(mx, off));
    float e = (t < K) ? expf(v - mx) : 0.f;
    float ss = e;
#pragma unroll
    for (int off = 1; off < 64; off <<= 1) ss += __shfl_xor(ss, off);
    if (t < K) sw[t] = e / ss;
  }
  __syncthreads();

  // fused gather: outT[b][m][c] = sum_j sw[j] * mvT[b][wn[j]][c]  (float4 rows)
  if (t < CV / 4) {
    const float4* tb4 = reinterpret_cast<const float4*>(mvT + (size_t)b * N * CV);
    float4 s = make_float4(0.f, 0.f, 0.f, 0.f);
#pragma unroll
    for (int j = 0; j < K; ++j) {
      float wj = sw[j];
      float4 v = tb4[(size_t)wn[j] * (CV / 4) + t];
      s.x += wj * v.x; s.y += wj * v.y; s.z += wj * v.z; s.w += wj * v.w;
    }
    reinterpret_cast<float4*>(outT + ((size_t)b * M + m) * CV)[t] = s;
  }
}

}  // namespace

extern "C" void kernel_launch(void* const* d_in, const int* in_sizes, int n_in,
                              void* d_out, int out_size, void* d_ws, size_t ws_size,
                              hipStream_t stream) {
  const float* mk = (const float*)d_in[0];
  const float* qk = (const float*)d_in[1];
  const float* mv = (const float*)d_in[2];
  float* out = (float*)d_out;

  char* w = (char*)d_ws;
  float* asq = (float*)w;
  size_t o = (size_t)B * N * sizeof(float);          // 103,680 B
  float* mvT = (float*)(w + o);
  o += (size_t)B * N * CV * sizeof(float);           // +39,813,120 B
  float* outT = (float*)(w + o);
  o += (size_t)B * M * CV * sizeof(float);           // +4,976,640 B
  float* aff = (float*)(w + o);

  // chunk M so the fp32 affinity buffer [B][mcAlloc][N] fits in workspace
  size_t avail = (ws_size > o) ? (ws_size - o) : 0;
  long cols = (long)(avail / ((size_t)B * N * sizeof(float)));
  int mcAlloc = (int)(cols & ~63L);
  if (mcAlloc < 64) mcAlloc = 64;      // best-effort floor
  if (mcAlloc > 1664) mcAlloc = 1664;  // single-chunk cap (covers M=1620)

  transpose_kernel<<<dim3((N + 63) / 64, CV / 64, B), 256, 0, stream>>>(mv, mvT);
  asq_kernel<<<(B * N + 255) / 256, 256, 0, stream>>>(mk, asq);

  for (int m0 = 0; m0 < M; m0 += mcAlloc) {
    int mcAct = (M - m0 < mcAlloc) ? (M - m0) : mcAlloc;
    dim3 ga((N + 255) / 256, (mcAct + 63) / 64, B);
    aff_kernel<<<ga, 256, 0, stream>>>(mk, qk, asq, aff, m0, mcAct, mcAlloc);
    topk_gather_kernel<<<dim3(mcAct, B), 256, 0, stream>>>(aff, mvT, m0, mcAlloc, outT);
  }

  transpose_out_kernel<<<dim3((M + 63) / 64, CV / 64, B), 256, 0, stream>>>(outT, out);
}